// Round 3
// baseline (1188.446 us; speedup 1.0000x reference)
//
#include <hip/hip_runtime.h>
#include <hip/hip_bf16.h>
#include <math.h>

#define NN 2048
#define DD 512
#define EE 65536
#define EPSV 0.5f

static const size_t SZ = (size_t)NN * NN;  // 4,194,304

// ---------------------------------------------------------------------------
// Build dense adjacency (f32) + row sums via edge scatter.
// adj lives in the adj_c region of d_out (f32) — reused as scratch, rewritten
// with the true adj_c before the kernel sequence ends.
// ---------------------------------------------------------------------------
__global__ __launch_bounds__(256) void build_adj(const int* __restrict__ row,
                                                 const int* __restrict__ col,
                                                 const float* __restrict__ attr,
                                                 float* __restrict__ adj,
                                                 float* __restrict__ rowsum) {
  int e = blockIdx.x * 256 + threadIdx.x;  // E is an exact multiple of 256
  float a = attr[e];
  atomicAdd(&adj[row[e] * NN + col[e]], a);
  atomicAdd(&rowsum[row[e]], a);
}

// ---------------------------------------------------------------------------
// Greedy maximal k-independent set (k=2), single block, all state in LDS.
// Double-buffered hops reproduce the reference's exact one-hop semantics.
// ---------------------------------------------------------------------------
__global__ __launch_bounds__(1024) void mis_kernel(const int* __restrict__ row,
                                                   const int* __restrict__ col,
                                                   const int* __restrict__ rank_g,
                                                   int* __restrict__ mis_flag) {
  __shared__ int rank_s[NN];
  __shared__ int mr[NN];
  __shared__ int tmp[NN];
  __shared__ int mis_s[NN];
  __shared__ int mk[NN];
  __shared__ int done;
  int t = threadIdx.x;

  for (int v = t; v < NN; v += 1024) {
    int rk = rank_g[v];
    rank_s[v] = rk;
    mr[v] = rk;
    mis_s[v] = 0;
  }
  __syncthreads();

  for (int round = 0; round < NN; ++round) {
    // --- 2 hops of min-propagation (message row -> col), keep self ---
    for (int h = 0; h < 2; ++h) {
      for (int v = t; v < NN; v += 1024) tmp[v] = mr[v];
      __syncthreads();
      for (int e = t; e < EE; e += 1024) atomicMin(&mr[col[e]], tmp[row[e]]);
      __syncthreads();
    }
    // --- mis |= (rank == mr); mk = mis ---
    for (int v = t; v < NN; v += 1024) {
      if (rank_s[v] == mr[v]) mis_s[v] = 1;
      mk[v] = mis_s[v];
    }
    __syncthreads();
    // --- 2 hops of OR-propagation ---
    for (int h = 0; h < 2; ++h) {
      for (int v = t; v < NN; v += 1024) tmp[v] = mk[v];
      __syncthreads();
      for (int e = t; e < EE; e += 1024) {
        if (tmp[row[e]]) mk[col[e]] = 1;  // benign race: all write 1
      }
      __syncthreads();
    }
    // --- convergence: all covered? ---
    int uncov = 0;
    for (int v = t; v < NN; v += 1024) uncov |= (mk[v] == 0);
    if (t == 0) done = 1;
    __syncthreads();
    if (uncov) done = 0;  // benign race: all write 0
    __syncthreads();
    if (done) break;
    for (int v = t; v < NN; v += 1024) mr[v] = mk[v] ? NN : rank_s[v];
    __syncthreads();
  }

  for (int v = t; v < NN; v += 1024) mis_flag[v] = mis_s[v];
}

// ---------------------------------------------------------------------------
// adj -> rw in place: offdiag = 0.5*adj/s', diag = adj/s' + 0.5  (s'=s>0?s:1)
// (reference computes new_diag BEFORE the (1-eps) scaling)
// ---------------------------------------------------------------------------
__global__ __launch_bounds__(256) void rw_transform(float* __restrict__ adj,
                                                    const float* __restrict__ rowsum) {
  int idx = blockIdx.x * 256 + threadIdx.x;  // over N*N, exact multiple
  int i = idx >> 11, j = idx & (NN - 1);
  float s = rowsum[i];
  s = (s > 0.f) ? s : 1.f;
  float v = adj[idx] / s;
  adj[idx] = (i == j) ? (v + EPSV) : (v * (1.f - EPSV));
}

// ---------------------------------------------------------------------------
// Fused c2-column + Gumbel-argmax. For each MIS column m:
//   c2[i][m] = sum_k rw[i][k]*rw[k][m];  logit = log(c2) + gumbel(u[i][m])
// Row-normalize of c is a per-row log-space constant -> argmax-invariant ->
// skipped. Winner folded into packed[i] via u64 atomicMax:
//   key = monotone-uint32(logit)<<32 | (2047-m)
// low-bits complement = np.argmax first-occurrence tie semantics. Sentinel 0
// (all-zero row) decodes to cluster 0 = np.argmax of an all -inf row.
// ---------------------------------------------------------------------------
__device__ inline unsigned int f32_key(float x) {
  unsigned int u = __float_as_uint(x);
  return (u & 0x80000000u) ? ~u : (u | 0x80000000u);
}

__global__ __launch_bounds__(256) void c2_argmax(const float* __restrict__ rw,
                                                 const float* __restrict__ u,
                                                 const int* __restrict__ mis_flag,
                                                 unsigned long long* __restrict__ packed) {
  int m = blockIdx.x;
  if (!mis_flag[m]) return;  // uniform per block
  int tile = blockIdx.y;     // 0..7 -> rows tile*256 .. tile*256+255
  __shared__ float colv[NN];
  for (int k = threadIdx.x; k < NN; k += 256) colv[k] = rw[k * NN + m];
  __syncthreads();
  int wid = threadIdx.x >> 6, lane = threadIdx.x & 63;
  for (int it = 0; it < 64; ++it) {
    int r = tile * 256 + wid * 64 + it;
    const float* rowp = rw + (size_t)r * NN;
    float acc = 0.f;
    for (int k = lane; k < NN; k += 64) acc += rowp[k] * colv[k];
    for (int off = 32; off > 0; off >>= 1) acc += __shfl_down(acc, off);
    if (lane == 0 && acc > 0.f) {
      float uu = u[(size_t)r * NN + m];
      float g = -logf(-logf(uu + 1e-20f) + 1e-20f);
      float logit = logf(acc) + g;
      unsigned long long key =
          ((unsigned long long)f32_key(logit) << 32) | (unsigned int)(NN - 1 - m);
      atomicMax(&packed[r], key);
    }
  }
}

// ---------------------------------------------------------------------------
// Decode packed winners into cluster ids + per-cluster counts.
// ---------------------------------------------------------------------------
__global__ __launch_bounds__(256) void cluster_decode(const unsigned long long* __restrict__ packed,
                                                      int* __restrict__ cluster,
                                                      int* __restrict__ counts) {
  int i = blockIdx.x * 256 + threadIdx.x;
  unsigned long long p = packed[i];
  int m = (p == 0ull) ? 0 : (NN - 1 - (int)(p & 0xFFFFFFFFull));
  cluster[i] = m;
  atomicAdd(&counts[m], 1);
}

// ---------------------------------------------------------------------------
// adj_c[cl[r], cl[c]] += attr  (edge-wise c_hard^T A c_hard, on original adj)
// ---------------------------------------------------------------------------
__global__ __launch_bounds__(256) void adjc_scatter(const int* __restrict__ row,
                                                    const int* __restrict__ col,
                                                    const float* __restrict__ attr,
                                                    const int* __restrict__ cluster,
                                                    float* __restrict__ adjc) {
  int e = blockIdx.x * 256 + threadIdx.x;
  int cr = cluster[row[e]], cc = cluster[col[e]];
  atomicAdd(&adjc[(size_t)cr * NN + cc], attr[e]);
}

// ---------------------------------------------------------------------------
// c_hard[a][b] and p_inv[a][b] = c_hard[b][a]/max(counts[a],1), written direct.
// ---------------------------------------------------------------------------
__global__ __launch_bounds__(256) void write_chpm(const int* __restrict__ cluster,
                                                  const int* __restrict__ counts,
                                                  float* __restrict__ out_ch,
                                                  float* __restrict__ out_pinv) {
  int idx = blockIdx.x * 256 + threadIdx.x;  // over N*N
  int a = idx >> 11, b = idx & (NN - 1);
  out_ch[idx] = (cluster[a] == b) ? 1.f : 0.f;
  float pv = 0.f;
  if (cluster[b] == a) {
    int c = counts[a];
    pv = 1.f / (float)(c > 0 ? c : 1);
  }
  out_pinv[idx] = pv;
}

// ---------------------------------------------------------------------------
__global__ __launch_bounds__(256) void write_mis(const int* __restrict__ mis_flag,
                                                 float* __restrict__ out_mis) {
  int i = blockIdx.x * 256 + threadIdx.x;  // over N
  out_mis[i] = mis_flag[i] ? 1.f : 0.f;
}

// ---------------------------------------------------------------------------
// x_pool accumulation directly into the (zeroed) f32 output region.
// ---------------------------------------------------------------------------
__global__ __launch_bounds__(256) void xpool_scatter(const float* __restrict__ x,
                                                     const int* __restrict__ cluster,
                                                     float* __restrict__ xp) {
  int idx = blockIdx.x * 256 + threadIdx.x;  // over N*D
  int i = idx >> 9;
  atomicAdd(&xp[cluster[i] * DD + (idx & (DD - 1))], x[idx]);
}

__global__ __launch_bounds__(256) void xpool_scale(float* __restrict__ xp,
                                                   const int* __restrict__ counts) {
  int idx = blockIdx.x * 256 + threadIdx.x;  // over N*D
  int c = counts[idx >> 9];
  xp[idx] = xp[idx] / (float)(c > 0 ? c : 1);
}

// ---------------------------------------------------------------------------
extern "C" void kernel_launch(void* const* d_in, const int* in_sizes, int n_in,
                              void* d_out, int out_size, void* d_ws, size_t ws_size,
                              hipStream_t stream) {
  const int*   edge_index = (const int*)d_in[0];
  const float* edge_attr  = (const float*)d_in[1];   // reference dtype: f32
  const float* x          = (const float*)d_in[2];
  const int*   rank       = (const int*)d_in[3];
  const float* u          = (const float*)d_in[4];
  float* out              = (float*)d_out;           // reference output dtype: f32

  const int* row = edge_index;
  const int* col = edge_index + EE;

  // output regions, concatenated in reference return order (all f32)
  float* out_adjc = out;                 // N*N — doubles as adj/rw scratch
  float* out_ch   = out + SZ;            // N*N
  float* out_pinv = out + 2 * SZ;        // N*N
  float* out_mis  = out + 3 * SZ;        // N
  float* out_xp   = out + 3 * SZ + NN;   // N*D

  // d_ws: only 48 KB of small arrays (robust to any plausible ws_size)
  unsigned long long* packed = (unsigned long long*)d_ws;  // N u64
  float* rowsum  = (float*)(packed + NN);                  // N
  int*   counts  = (int*)(rowsum + NN);                    // N
  int*   mis_flag = counts + NN;                           // N
  int*   cluster  = mis_flag + NN;                         // N

  // zero the accumulators we own (out/ws are poisoned 0xAA before timed calls)
  hipMemsetAsync(out_adjc, 0, SZ * sizeof(float), stream);
  hipMemsetAsync(out_xp, 0, (size_t)NN * DD * sizeof(float), stream);
  hipMemsetAsync(d_ws, 0, NN * sizeof(unsigned long long) + 4 * NN * sizeof(int), stream);

  build_adj<<<EE / 256, 256, 0, stream>>>(row, col, edge_attr, out_adjc, rowsum);
  mis_kernel<<<1, 1024, 0, stream>>>(row, col, rank, mis_flag);
  rw_transform<<<(NN * NN) / 256, 256, 0, stream>>>(out_adjc, rowsum);
  c2_argmax<<<dim3(NN, 8), 256, 0, stream>>>(out_adjc, u, mis_flag, packed);
  cluster_decode<<<NN / 256, 256, 0, stream>>>(packed, cluster, counts);

  // rw no longer needed: rewrite the region with the real adj_c
  hipMemsetAsync(out_adjc, 0, SZ * sizeof(float), stream);
  adjc_scatter<<<EE / 256, 256, 0, stream>>>(row, col, edge_attr, cluster, out_adjc);

  write_chpm<<<(NN * NN) / 256, 256, 0, stream>>>(cluster, counts, out_ch, out_pinv);
  write_mis<<<NN / 256, 256, 0, stream>>>(mis_flag, out_mis);
  xpool_scatter<<<(NN * DD) / 256, 256, 0, stream>>>(x, cluster, out_xp);
  xpool_scale<<<(NN * DD) / 256, 256, 0, stream>>>(out_xp, counts);
}

// Round 4
// 445.287 us; speedup vs baseline: 2.6689x; 2.6689x over previous
//
#include <hip/hip_runtime.h>
#include <hip/hip_bf16.h>
#include <math.h>

#define NN 2048
#define DD 512
#define EE 65536
#define EPSV 0.5f

static const size_t SZ = (size_t)NN * NN;  // 4,194,304

// ---------------------------------------------------------------------------
// Build dense adjacency (f32) + row sums via edge scatter.
// ---------------------------------------------------------------------------
__global__ __launch_bounds__(256) void build_adj(const int* __restrict__ row,
                                                 const int* __restrict__ col,
                                                 const float* __restrict__ attr,
                                                 float* __restrict__ adj,
                                                 float* __restrict__ rowsum) {
  int e = blockIdx.x * 256 + threadIdx.x;  // E exact multiple of 256
  float a = attr[e];
  atomicAdd(&adj[row[e] * NN + col[e]], a);
  atomicAdd(&rowsum[row[e]], a);
}

// ---------------------------------------------------------------------------
// Greedy maximal k-independent set (k=2), single block, state in LDS.
// All 64 edges/thread are cached in registers as packed (row<<11)|col —
// zero global traffic inside the data-dependent convergence loop.
// MIS list compaction is UNORDERED (atomicAdd) — legal because the consumer
// (c2_argmax) resolves ties via the packed-key atomicMax, not list order.
// ---------------------------------------------------------------------------
__global__ __launch_bounds__(1024) void mis_kernel(const int* __restrict__ row,
                                                   const int* __restrict__ col,
                                                   const int* __restrict__ rank_g,
                                                   int* __restrict__ mis_flag,
                                                   int* __restrict__ mis_list,
                                                   int* __restrict__ mis_count) {
  __shared__ int rank_s[NN];
  __shared__ int mr[NN];
  __shared__ int tmp[NN];
  __shared__ int mis_s[NN];
  __shared__ int mk[NN];
  __shared__ int done;
  __shared__ int cnt;
  int t = threadIdx.x;

  unsigned pe[64];  // packed edges, register-resident (full unroll)
#pragma unroll
  for (int i = 0; i < 64; ++i) {
    int e = t + 1024 * i;  // coalesced
    pe[i] = ((unsigned)row[e] << 11) | (unsigned)col[e];
  }

  for (int v = t; v < NN; v += 1024) {
    int rk = rank_g[v];
    rank_s[v] = rk;
    mr[v] = rk;
    mis_s[v] = 0;
  }
  if (t == 0) cnt = 0;
  __syncthreads();

  for (int round = 0; round < NN; ++round) {
    // --- 2 hops of min-propagation (message row -> col), keep self ---
    for (int h = 0; h < 2; ++h) {
      for (int v = t; v < NN; v += 1024) tmp[v] = mr[v];
      __syncthreads();
#pragma unroll
      for (int i = 0; i < 64; ++i) {
        unsigned p = pe[i];
        atomicMin(&mr[p & 2047u], tmp[p >> 11]);
      }
      __syncthreads();
    }
    // --- mis |= (rank == mr); mk = mis ---
    for (int v = t; v < NN; v += 1024) {
      if (rank_s[v] == mr[v]) mis_s[v] = 1;
      mk[v] = mis_s[v];
    }
    __syncthreads();
    // --- 2 hops of OR-propagation ---
    for (int h = 0; h < 2; ++h) {
      for (int v = t; v < NN; v += 1024) tmp[v] = mk[v];
      __syncthreads();
#pragma unroll
      for (int i = 0; i < 64; ++i) {
        unsigned p = pe[i];
        if (tmp[p >> 11]) mk[p & 2047u] = 1;  // benign race: all write 1
      }
      __syncthreads();
    }
    // --- convergence: all covered? (idempotent body, early-exit only) ---
    int uncov = 0;
    for (int v = t; v < NN; v += 1024) uncov |= (mk[v] == 0);
    if (t == 0) done = 1;
    __syncthreads();
    if (uncov) done = 0;  // benign race: all write 0
    __syncthreads();
    if (done) break;
    for (int v = t; v < NN; v += 1024) mr[v] = mk[v] ? NN : rank_s[v];
    __syncthreads();
  }

  for (int v = t; v < NN; v += 1024) {
    mis_flag[v] = mis_s[v];
    if (mis_s[v]) mis_list[atomicAdd(&cnt, 1)] = v;  // unordered compaction
  }
  __syncthreads();
  if (t == 0) *mis_count = cnt;
}

// ---------------------------------------------------------------------------
// adj -> rw in place: offdiag = 0.5*adj/s', diag = adj/s' + 0.5  (s'=s>0?s:1)
// ---------------------------------------------------------------------------
__global__ __launch_bounds__(256) void rw_transform(float* __restrict__ adj,
                                                    const float* __restrict__ rowsum) {
  int idx = blockIdx.x * 256 + threadIdx.x;
  int i = idx >> 11, j = idx & (NN - 1);
  float s = rowsum[i];
  s = (s > 0.f) ? s : 1.f;
  float v = adj[idx] / s;
  adj[idx] = (i == j) ? (v + EPSV) : (v * (1.f - EPSV));
}

// ---------------------------------------------------------------------------
// Gather the M MIS columns of rw into compact Bc[t][k] (row-major, k fast).
// ---------------------------------------------------------------------------
__global__ __launch_bounds__(256) void gather_cols(const float* __restrict__ rw,
                                                   const int* __restrict__ mis_list,
                                                   const int* __restrict__ mis_count,
                                                   float* __restrict__ Bc) {
  int total = (*mis_count) * NN;
  for (int idx = blockIdx.x * 256 + threadIdx.x; idx < total; idx += gridDim.x * 256) {
    int tcol = idx >> 11, k = idx & (NN - 1);
    Bc[idx] = rw[(size_t)k * NN + mis_list[tcol]];
  }
}

// ---------------------------------------------------------------------------
// Fused c2-column + Gumbel-argmax, v2.
// Job = (MIS column t, 32-row tile). Each lane register-caches its 32-element
// slice of the column (8 x float4) and streams 8 rows as 8 independent float4
// loads each -> deep memory-level parallelism. Fixed shuffle tree (xor 32..1)
// keeps the k-sum deterministic. Winner via u64 atomicMax (associative ->
// order-free); key low bits (2047-m) reproduce np.argmax first-occurrence.
// ---------------------------------------------------------------------------
__device__ inline unsigned int f32_key(float x) {
  unsigned int u = __float_as_uint(x);
  return (u & 0x80000000u) ? ~u : (u | 0x80000000u);
}
__device__ inline float dot4(float4 a, float4 b) {
  return ((a.x * b.x + a.y * b.y) + (a.z * b.z + a.w * b.w));
}

__global__ __launch_bounds__(256) void c2_argmax(const float* __restrict__ rw,
                                                 const float* __restrict__ Bc,
                                                 const float* __restrict__ u,
                                                 const int* __restrict__ mis_list,
                                                 const int* __restrict__ mis_count,
                                                 unsigned long long* __restrict__ packed) {
  int M = *mis_count;
  int njobs = M * 64;  // 64 tiles of 32 rows
  int lane = threadIdx.x & 63, w = threadIdx.x >> 6;
  for (int j = blockIdx.x; j < njobs; j += gridDim.x) {
    int tcol = j >> 6, tile = j & 63;
    int m = mis_list[tcol];
    const float4* cb = (const float4*)(Bc + (size_t)tcol * NN);
    float4 c0 = cb[lane], c1 = cb[64 + lane], c2v = cb[128 + lane], c3 = cb[192 + lane];
    float4 c4 = cb[256 + lane], c5 = cb[320 + lane], c6 = cb[384 + lane], c7 = cb[448 + lane];
    int rbase = tile * 32 + w * 8;
#pragma unroll
    for (int it = 0; it < 8; ++it) {
      int r = rbase + it;
      const float4* rp = (const float4*)(rw + (size_t)r * NN);
      float4 a0 = rp[lane], a1 = rp[64 + lane], a2 = rp[128 + lane], a3 = rp[192 + lane];
      float4 a4 = rp[256 + lane], a5 = rp[320 + lane], a6 = rp[384 + lane], a7 = rp[448 + lane];
      float s01 = dot4(a0, c0) + dot4(a1, c1);
      float s23 = dot4(a2, c2v) + dot4(a3, c3);
      float s45 = dot4(a4, c4) + dot4(a5, c5);
      float s67 = dot4(a6, c6) + dot4(a7, c7);
      float s = (s01 + s23) + (s45 + s67);
      s += __shfl_xor(s, 32);
      s += __shfl_xor(s, 16);
      s += __shfl_xor(s, 8);
      s += __shfl_xor(s, 4);
      s += __shfl_xor(s, 2);
      s += __shfl_xor(s, 1);
      if (lane == 0 && s > 0.f) {
        float uu = u[(size_t)r * NN + m];
        float g = -logf(-logf(uu + 1e-20f) + 1e-20f);
        float logit = logf(s) + g;
        unsigned long long key =
            ((unsigned long long)f32_key(logit) << 32) | (unsigned int)(NN - 1 - m);
        atomicMax(&packed[r], key);
      }
    }
  }
}

// ---------------------------------------------------------------------------
// Decode packed winners into cluster ids + per-cluster counts.
// ---------------------------------------------------------------------------
__global__ __launch_bounds__(256) void cluster_decode(const unsigned long long* __restrict__ packed,
                                                      int* __restrict__ cluster,
                                                      int* __restrict__ counts) {
  int i = blockIdx.x * 256 + threadIdx.x;
  unsigned long long p = packed[i];
  int m = (p == 0ull) ? 0 : (NN - 1 - (int)(p & 0xFFFFFFFFull));
  cluster[i] = m;
  atomicAdd(&counts[m], 1);
}

// ---------------------------------------------------------------------------
__global__ __launch_bounds__(256) void adjc_scatter(const int* __restrict__ row,
                                                    const int* __restrict__ col,
                                                    const float* __restrict__ attr,
                                                    const int* __restrict__ cluster,
                                                    float* __restrict__ adjc) {
  int e = blockIdx.x * 256 + threadIdx.x;
  int cr = cluster[row[e]], cc = cluster[col[e]];
  atomicAdd(&adjc[(size_t)cr * NN + cc], attr[e]);
}

// ---------------------------------------------------------------------------
__global__ __launch_bounds__(256) void write_chpm(const int* __restrict__ cluster,
                                                  const int* __restrict__ counts,
                                                  float* __restrict__ out_ch,
                                                  float* __restrict__ out_pinv) {
  int idx = blockIdx.x * 256 + threadIdx.x;  // over N*N
  int a = idx >> 11, b = idx & (NN - 1);
  out_ch[idx] = (cluster[a] == b) ? 1.f : 0.f;
  float pv = 0.f;
  if (cluster[b] == a) {
    int c = counts[a];
    pv = 1.f / (float)(c > 0 ? c : 1);
  }
  out_pinv[idx] = pv;
}

// ---------------------------------------------------------------------------
__global__ __launch_bounds__(256) void write_mis(const int* __restrict__ mis_flag,
                                                 float* __restrict__ out_mis) {
  int i = blockIdx.x * 256 + threadIdx.x;
  out_mis[i] = mis_flag[i] ? 1.f : 0.f;
}

// ---------------------------------------------------------------------------
__global__ __launch_bounds__(256) void xpool_scatter(const float* __restrict__ x,
                                                     const int* __restrict__ cluster,
                                                     float* __restrict__ xp) {
  int idx = blockIdx.x * 256 + threadIdx.x;  // over N*D
  int i = idx >> 9;
  atomicAdd(&xp[cluster[i] * DD + (idx & (DD - 1))], x[idx]);
}

__global__ __launch_bounds__(256) void xpool_scale(float* __restrict__ xp,
                                                   const int* __restrict__ counts) {
  int idx = blockIdx.x * 256 + threadIdx.x;
  int c = counts[idx >> 9];
  xp[idx] = xp[idx] / (float)(c > 0 ? c : 1);
}

// ---------------------------------------------------------------------------
extern "C" void kernel_launch(void* const* d_in, const int* in_sizes, int n_in,
                              void* d_out, int out_size, void* d_ws, size_t ws_size,
                              hipStream_t stream) {
  const int*   edge_index = (const int*)d_in[0];
  const float* edge_attr  = (const float*)d_in[1];
  const float* x          = (const float*)d_in[2];
  const int*   rank       = (const int*)d_in[3];
  const float* u          = (const float*)d_in[4];
  float* out              = (float*)d_out;  // f32 outputs, concatenated

  const int* row = edge_index;
  const int* col = edge_index + EE;

  float* out_adjc = out;                 // N*N — doubles as adj/rw scratch
  float* out_ch   = out + SZ;            // N*N — doubles as Bc scratch
  float* out_pinv = out + 2 * SZ;        // N*N
  float* out_mis  = out + 3 * SZ;        // N
  float* out_xp   = out + 3 * SZ + NN;   // N*D

  // d_ws: ~56 KB of small arrays
  unsigned long long* packed = (unsigned long long*)d_ws;  // N u64
  float* rowsum   = (float*)(packed + NN);                 // N
  int*   counts   = (int*)(rowsum + NN);                   // N
  int*   mis_flag = counts + NN;                           // N
  int*   cluster  = mis_flag + NN;                         // N
  int*   mis_list = cluster + NN;                          // N
  int*   mis_count = mis_list + NN;                        // 1

  hipMemsetAsync(out_adjc, 0, SZ * sizeof(float), stream);
  hipMemsetAsync(out_xp, 0, (size_t)NN * DD * sizeof(float), stream);
  hipMemsetAsync(d_ws, 0, NN * sizeof(unsigned long long) + 4 * NN * sizeof(int), stream);

  build_adj<<<EE / 256, 256, 0, stream>>>(row, col, edge_attr, out_adjc, rowsum);
  mis_kernel<<<1, 1024, 0, stream>>>(row, col, rank, mis_flag, mis_list, mis_count);
  rw_transform<<<(NN * NN) / 256, 256, 0, stream>>>(out_adjc, rowsum);
  gather_cols<<<256, 256, 0, stream>>>(out_adjc, mis_list, mis_count, out_ch);
  c2_argmax<<<2048, 256, 0, stream>>>(out_adjc, out_ch, u, mis_list, mis_count, packed);
  cluster_decode<<<NN / 256, 256, 0, stream>>>(packed, cluster, counts);

  // rw no longer needed: rewrite the region with the real adj_c
  hipMemsetAsync(out_adjc, 0, SZ * sizeof(float), stream);
  adjc_scatter<<<EE / 256, 256, 0, stream>>>(row, col, edge_attr, cluster, out_adjc);

  write_chpm<<<(NN * NN) / 256, 256, 0, stream>>>(cluster, counts, out_ch, out_pinv);
  write_mis<<<NN / 256, 256, 0, stream>>>(mis_flag, out_mis);
  xpool_scatter<<<(NN * DD) / 256, 256, 0, stream>>>(x, cluster, out_xp);
  xpool_scale<<<(NN * DD) / 256, 256, 0, stream>>>(out_xp, counts);
}

// Round 5
// 439.160 us; speedup vs baseline: 2.7062x; 1.0140x over previous
//
#include <hip/hip_runtime.h>
#include <hip/hip_bf16.h>
#include <math.h>

#define NN 2048
#define DD 512
#define EE 65536
#define EPSV 0.5f
#define SEN 2048  // covered-rank sentinel (= n in the reference)

static const size_t SZ = (size_t)NN * NN;  // 4,194,304

// ---------------------------------------------------------------------------
// Build dense adjacency (f32) + row sums via edge scatter.
// ---------------------------------------------------------------------------
__global__ __launch_bounds__(256) void build_adj(const int* __restrict__ row,
                                                 const int* __restrict__ col,
                                                 const float* __restrict__ attr,
                                                 float* __restrict__ adj,
                                                 float* __restrict__ rowsum) {
  int e = blockIdx.x * 256 + threadIdx.x;  // E exact multiple of 256
  float a = attr[e];
  atomicAdd(&adj[row[e] * NN + col[e]], a);
  atomicAdd(&rowsum[row[e]], a);
}

// ---------------------------------------------------------------------------
// CSR build (by row; both propagations send row->col). Within-row order is
// nondeterministic (atomic fill) but all consumers are order-free.
// ---------------------------------------------------------------------------
__global__ __launch_bounds__(256) void csr_count(const int* __restrict__ row,
                                                 int* __restrict__ degree) {
  int e = blockIdx.x * 256 + threadIdx.x;
  atomicAdd(&degree[row[e]], 1);
}

__global__ __launch_bounds__(1024) void csr_scan(const int* __restrict__ degree,
                                                 int* __restrict__ row_ptr,
                                                 int* __restrict__ fill_ptr) {
  __shared__ int a[NN], b[NN];
  int t = threadIdx.x;
  for (int v = t; v < NN; v += 1024) a[v] = degree[v];
  __syncthreads();
  int* src = a;
  int* dst = b;
  for (int off = 1; off < NN; off <<= 1) {  // Hillis-Steele inclusive scan
    for (int v = t; v < NN; v += 1024)
      dst[v] = src[v] + (v >= off ? src[v - off] : 0);
    __syncthreads();
    int* tmp = src; src = dst; dst = tmp;
  }
  for (int v = t; v < NN; v += 1024) {
    int excl = src[v] - degree[v];
    row_ptr[v] = excl;
    fill_ptr[v] = excl;
  }
  if (t == 0) row_ptr[NN] = EE;
}

__global__ __launch_bounds__(256) void csr_fill(const int* __restrict__ row,
                                                const int* __restrict__ col,
                                                int* __restrict__ fill_ptr,
                                                unsigned short* __restrict__ colidx) {
  int e = blockIdx.x * 256 + threadIdx.x;
  int pos = atomicAdd(&fill_ptr[row[e]], 1);
  colidx[pos] = (unsigned short)col[e];
}

// ---------------------------------------------------------------------------
// Greedy maximal k-independent set (k=2), single block, state in LDS.
// Work-reduced but EXACT vs reference:
//  - min-prop: sources with value SEN are skipped (min(x,SEN) is a no-op).
//  - OR-prop runs on the per-round DELTA only; mask is monotone and OR-prop
//    distributes over union, so mask |= 2hop(delta) == reference's mask.
//  - source-centric CSR: inactive source skips all its edges with 1 LDS read.
// Hop boundaries preserved via double-buffered snapshots.
// ---------------------------------------------------------------------------
__global__ __launch_bounds__(1024) void mis_kernel(const int* __restrict__ row_ptr_g,
                                                   const unsigned short* __restrict__ colidx,
                                                   const int* __restrict__ rank_g,
                                                   int* __restrict__ mis_flag,
                                                   int* __restrict__ mis_list,
                                                   int* __restrict__ mis_count) {
  __shared__ int rank_s[NN];
  __shared__ int mr[NN];
  __shared__ int tmp[NN];
  __shared__ int cov[NN];
  __shared__ int dly[NN];
  __shared__ int mis_s[NN];
  __shared__ int row_ptr_s[NN + 1];
  __shared__ int done;
  __shared__ int cnt;
  int t = threadIdx.x;

  for (int v = t; v < NN; v += 1024) {
    int rk = rank_g[v];
    rank_s[v] = rk;
    mr[v] = rk;
    cov[v] = 0;
    mis_s[v] = 0;
    row_ptr_s[v] = row_ptr_g[v];
  }
  if (t == 0) {
    row_ptr_s[NN] = EE;
    cnt = 0;
  }
  __syncthreads();

  for (int round = 0; round < NN; ++round) {
    // --- 2 hops of min-propagation (row -> col); skip no-op sources ---
    for (int h = 0; h < 2; ++h) {
      for (int v = t; v < NN; v += 1024) tmp[v] = mr[v];
      __syncthreads();
      for (int v = t; v < NN; v += 1024) {
        int val = tmp[v];
        if (val != SEN) {
          int e0 = row_ptr_s[v], e1 = row_ptr_s[v + 1];
          for (int e = e0; e < e1; ++e) atomicMin(&mr[colidx[e]], val);
        }
      }
      __syncthreads();
    }
    // --- delta = newly selected; mis |= delta ---
    for (int v = t; v < NN; v += 1024) {
      int nw = (rank_s[v] == mr[v]) ? 1 : 0;  // can only fire for new nodes
      if (nw) mis_s[v] = 1;
      dly[v] = nw;
    }
    __syncthreads();
    // --- 2 hops of OR-propagation over the delta frontier ---
    for (int h = 0; h < 2; ++h) {
      for (int v = t; v < NN; v += 1024) tmp[v] = dly[v];
      __syncthreads();
      for (int v = t; v < NN; v += 1024) {
        if (tmp[v]) {
          int e0 = row_ptr_s[v], e1 = row_ptr_s[v + 1];
          for (int e = e0; e < e1; ++e) dly[colidx[e]] = 1;  // benign race
        }
      }
      __syncthreads();
    }
    // --- fold delta into mask; convergence check ---
    int uncov = 0;
    for (int v = t; v < NN; v += 1024) {
      int cv = cov[v] | dly[v];
      cov[v] = cv;
      uncov |= (cv == 0);
    }
    if (t == 0) done = 1;
    __syncthreads();
    if (uncov) done = 0;  // benign race: all write 0
    __syncthreads();
    if (done) break;
    // --- mr = covered ? SEN : rank ---
    for (int v = t; v < NN; v += 1024) mr[v] = cov[v] ? SEN : rank_s[v];
    __syncthreads();
  }

  for (int v = t; v < NN; v += 1024) {
    mis_flag[v] = mis_s[v];
    if (mis_s[v]) mis_list[atomicAdd(&cnt, 1)] = v;  // unordered (consumers order-free)
  }
  __syncthreads();
  if (t == 0) *mis_count = cnt;
}

// ---------------------------------------------------------------------------
// adj -> rw in place: offdiag = 0.5*adj/s', diag = adj/s' + 0.5  (s'=s>0?s:1)
// ---------------------------------------------------------------------------
__global__ __launch_bounds__(256) void rw_transform(float* __restrict__ adj,
                                                    const float* __restrict__ rowsum) {
  int idx = blockIdx.x * 256 + threadIdx.x;
  int i = idx >> 11, j = idx & (NN - 1);
  float s = rowsum[i];
  s = (s > 0.f) ? s : 1.f;
  float v = adj[idx] / s;
  adj[idx] = (i == j) ? (v + EPSV) : (v * (1.f - EPSV));
}

// ---------------------------------------------------------------------------
// Gather the M MIS columns of rw into compact Bc[t][k] (row-major, k fast).
// ---------------------------------------------------------------------------
__global__ __launch_bounds__(256) void gather_cols(const float* __restrict__ rw,
                                                   const int* __restrict__ mis_list,
                                                   const int* __restrict__ mis_count,
                                                   float* __restrict__ Bc) {
  int total = (*mis_count) * NN;
  for (int idx = blockIdx.x * 256 + threadIdx.x; idx < total; idx += gridDim.x * 256) {
    int tcol = idx >> 11, k = idx & (NN - 1);
    Bc[idx] = rw[(size_t)k * NN + mis_list[tcol]];
  }
}

// ---------------------------------------------------------------------------
// Fused c2-column + Gumbel-argmax (register-cached column slices, float4 MLP,
// deterministic shuffle tree, order-free u64 atomicMax winner fold).
// ---------------------------------------------------------------------------
__device__ inline unsigned int f32_key(float x) {
  unsigned int u = __float_as_uint(x);
  return (u & 0x80000000u) ? ~u : (u | 0x80000000u);
}
__device__ inline float dot4(float4 a, float4 b) {
  return ((a.x * b.x + a.y * b.y) + (a.z * b.z + a.w * b.w));
}

__global__ __launch_bounds__(256) void c2_argmax(const float* __restrict__ rw,
                                                 const float* __restrict__ Bc,
                                                 const float* __restrict__ u,
                                                 const int* __restrict__ mis_list,
                                                 const int* __restrict__ mis_count,
                                                 unsigned long long* __restrict__ packed) {
  int M = *mis_count;
  int njobs = M * 64;  // 64 tiles of 32 rows
  int lane = threadIdx.x & 63, w = threadIdx.x >> 6;
  for (int j = blockIdx.x; j < njobs; j += gridDim.x) {
    int tcol = j >> 6, tile = j & 63;
    int m = mis_list[tcol];
    const float4* cb = (const float4*)(Bc + (size_t)tcol * NN);
    float4 c0 = cb[lane], c1 = cb[64 + lane], c2v = cb[128 + lane], c3 = cb[192 + lane];
    float4 c4 = cb[256 + lane], c5 = cb[320 + lane], c6 = cb[384 + lane], c7 = cb[448 + lane];
    int rbase = tile * 32 + w * 8;
#pragma unroll
    for (int it = 0; it < 8; ++it) {
      int r = rbase + it;
      const float4* rp = (const float4*)(rw + (size_t)r * NN);
      float4 a0 = rp[lane], a1 = rp[64 + lane], a2 = rp[128 + lane], a3 = rp[192 + lane];
      float4 a4 = rp[256 + lane], a5 = rp[320 + lane], a6 = rp[384 + lane], a7 = rp[448 + lane];
      float s01 = dot4(a0, c0) + dot4(a1, c1);
      float s23 = dot4(a2, c2v) + dot4(a3, c3);
      float s45 = dot4(a4, c4) + dot4(a5, c5);
      float s67 = dot4(a6, c6) + dot4(a7, c7);
      float s = (s01 + s23) + (s45 + s67);
      s += __shfl_xor(s, 32);
      s += __shfl_xor(s, 16);
      s += __shfl_xor(s, 8);
      s += __shfl_xor(s, 4);
      s += __shfl_xor(s, 2);
      s += __shfl_xor(s, 1);
      if (lane == 0 && s > 0.f) {
        float uu = u[(size_t)r * NN + m];
        float g = -logf(-logf(uu + 1e-20f) + 1e-20f);
        float logit = logf(s) + g;
        unsigned long long key =
            ((unsigned long long)f32_key(logit) << 32) | (unsigned int)(NN - 1 - m);
        atomicMax(&packed[r], key);
      }
    }
  }
}

// ---------------------------------------------------------------------------
__global__ __launch_bounds__(256) void cluster_decode(const unsigned long long* __restrict__ packed,
                                                      int* __restrict__ cluster,
                                                      int* __restrict__ counts) {
  int i = blockIdx.x * 256 + threadIdx.x;
  unsigned long long p = packed[i];
  int m = (p == 0ull) ? 0 : (NN - 1 - (int)(p & 0xFFFFFFFFull));
  cluster[i] = m;
  atomicAdd(&counts[m], 1);
}

// ---------------------------------------------------------------------------
__global__ __launch_bounds__(256) void adjc_scatter(const int* __restrict__ row,
                                                    const int* __restrict__ col,
                                                    const float* __restrict__ attr,
                                                    const int* __restrict__ cluster,
                                                    float* __restrict__ adjc) {
  int e = blockIdx.x * 256 + threadIdx.x;
  int cr = cluster[row[e]], cc = cluster[col[e]];
  atomicAdd(&adjc[(size_t)cr * NN + cc], attr[e]);
}

// ---------------------------------------------------------------------------
__global__ __launch_bounds__(256) void write_chpm(const int* __restrict__ cluster,
                                                  const int* __restrict__ counts,
                                                  float* __restrict__ out_ch,
                                                  float* __restrict__ out_pinv) {
  int idx = blockIdx.x * 256 + threadIdx.x;  // over N*N
  int a = idx >> 11, b = idx & (NN - 1);
  out_ch[idx] = (cluster[a] == b) ? 1.f : 0.f;
  float pv = 0.f;
  if (cluster[b] == a) {
    int c = counts[a];
    pv = 1.f / (float)(c > 0 ? c : 1);
  }
  out_pinv[idx] = pv;
}

// ---------------------------------------------------------------------------
__global__ __launch_bounds__(256) void write_mis(const int* __restrict__ mis_flag,
                                                 float* __restrict__ out_mis) {
  int i = blockIdx.x * 256 + threadIdx.x;
  out_mis[i] = mis_flag[i] ? 1.f : 0.f;
}

// ---------------------------------------------------------------------------
__global__ __launch_bounds__(256) void xpool_scatter(const float* __restrict__ x,
                                                     const int* __restrict__ cluster,
                                                     float* __restrict__ xp) {
  int idx = blockIdx.x * 256 + threadIdx.x;  // over N*D
  int i = idx >> 9;
  atomicAdd(&xp[cluster[i] * DD + (idx & (DD - 1))], x[idx]);
}

__global__ __launch_bounds__(256) void xpool_scale(float* __restrict__ xp,
                                                   const int* __restrict__ counts) {
  int idx = blockIdx.x * 256 + threadIdx.x;
  int c = counts[idx >> 9];
  xp[idx] = xp[idx] / (float)(c > 0 ? c : 1);
}

// ---------------------------------------------------------------------------
extern "C" void kernel_launch(void* const* d_in, const int* in_sizes, int n_in,
                              void* d_out, int out_size, void* d_ws, size_t ws_size,
                              hipStream_t stream) {
  const int*   edge_index = (const int*)d_in[0];
  const float* edge_attr  = (const float*)d_in[1];
  const float* x          = (const float*)d_in[2];
  const int*   rank       = (const int*)d_in[3];
  const float* u          = (const float*)d_in[4];
  float* out              = (float*)d_out;  // f32 outputs, concatenated

  const int* row = edge_index;
  const int* col = edge_index + EE;

  float* out_adjc = out;                 // N*N — doubles as adj/rw scratch
  float* out_ch   = out + SZ;            // N*N — doubles as Bc scratch
  float* out_pinv = out + 2 * SZ;        // N*N
  float* out_mis  = out + 3 * SZ;        // N
  float* out_xp   = out + 3 * SZ + NN;   // N*D

  // d_ws layout (~220 KB)
  unsigned long long* packed = (unsigned long long*)d_ws;  // N u64
  float* rowsum    = (float*)(packed + NN);                // N
  int*   counts    = (int*)(rowsum + NN);                  // N
  int*   mis_flag  = counts + NN;                          // N
  int*   cluster   = mis_flag + NN;                        // N
  int*   mis_list  = cluster + NN;                         // N
  int*   mis_count = mis_list + NN;                        // 1
  int*   degree    = mis_count + 1;                        // N
  int*   fill_ptr  = degree + NN;                          // N
  int*   row_ptr   = fill_ptr + NN;                        // N+1
  unsigned short* colidx = (unsigned short*)(row_ptr + NN + 1);  // E u16

  // zero: packed..mis_count plus degree (fill_ptr/row_ptr written by scan)
  hipMemsetAsync(out_adjc, 0, SZ * sizeof(float), stream);
  hipMemsetAsync(out_xp, 0, (size_t)NN * DD * sizeof(float), stream);
  hipMemsetAsync(d_ws, 0,
                 NN * sizeof(unsigned long long) + (5 * NN + 1 + NN) * sizeof(int), stream);

  build_adj<<<EE / 256, 256, 0, stream>>>(row, col, edge_attr, out_adjc, rowsum);
  csr_count<<<EE / 256, 256, 0, stream>>>(row, degree);
  csr_scan<<<1, 1024, 0, stream>>>(degree, row_ptr, fill_ptr);
  csr_fill<<<EE / 256, 256, 0, stream>>>(row, col, fill_ptr, colidx);
  mis_kernel<<<1, 1024, 0, stream>>>(row_ptr, colidx, rank, mis_flag, mis_list, mis_count);
  rw_transform<<<(NN * NN) / 256, 256, 0, stream>>>(out_adjc, rowsum);
  gather_cols<<<256, 256, 0, stream>>>(out_adjc, mis_list, mis_count, out_ch);
  c2_argmax<<<2048, 256, 0, stream>>>(out_adjc, out_ch, u, mis_list, mis_count, packed);
  cluster_decode<<<NN / 256, 256, 0, stream>>>(packed, cluster, counts);

  // rw no longer needed: rewrite the region with the real adj_c
  hipMemsetAsync(out_adjc, 0, SZ * sizeof(float), stream);
  adjc_scatter<<<EE / 256, 256, 0, stream>>>(row, col, edge_attr, cluster, out_adjc);

  write_chpm<<<(NN * NN) / 256, 256, 0, stream>>>(cluster, counts, out_ch, out_pinv);
  write_mis<<<NN / 256, 256, 0, stream>>>(mis_flag, out_mis);
  xpool_scatter<<<(NN * DD) / 256, 256, 0, stream>>>(x, cluster, out_xp);
  xpool_scale<<<(NN * DD) / 256, 256, 0, stream>>>(out_xp, counts);
}

// Round 6
// 318.299 us; speedup vs baseline: 3.7337x; 1.3797x over previous
//
#include <hip/hip_runtime.h>
#include <hip/hip_bf16.h>
#include <math.h>
#include <stdint.h>

#define NN 2048
#define DD 512
#define EE 65536
#define EPSV 0.5f
#define SEN 2048  // covered-rank sentinel (= n in the reference)

static const size_t SZ = (size_t)NN * NN;  // 4,194,304

// ---------------------------------------------------------------------------
// Build dense adjacency (f32) + row sums via edge scatter.
// ---------------------------------------------------------------------------
__global__ __launch_bounds__(256) void build_adj(const int* __restrict__ row,
                                                 const int* __restrict__ col,
                                                 const float* __restrict__ attr,
                                                 float* __restrict__ adj,
                                                 float* __restrict__ rowsum) {
  int e = blockIdx.x * 256 + threadIdx.x;  // E exact multiple of 256
  float a = attr[e];
  atomicAdd(&adj[row[e] * NN + col[e]], a);
  atomicAdd(&rowsum[row[e]], a);
}

// ---------------------------------------------------------------------------
// CSR build, rows padded to a multiple of 16 edges with SELF-edges.
// Self-edges are exact: reference prop_min keeps self (min(..., r)) and
// OR-prop to self is idempotent. Within-row order nondeterministic (atomic
// fill) but all consumers are order-free (min / idempotent OR).
// ---------------------------------------------------------------------------
__global__ __launch_bounds__(256) void csr_count(const int* __restrict__ row,
                                                 int* __restrict__ degree) {
  int e = blockIdx.x * 256 + threadIdx.x;
  atomicAdd(&degree[row[e]], 1);
}

__global__ __launch_bounds__(1024) void csr_scan(const int* __restrict__ degree,
                                                 int* __restrict__ row_ptr,
                                                 int* __restrict__ fill_ptr) {
  __shared__ int a[NN], b[NN];
  int t = threadIdx.x;
  for (int v = t; v < NN; v += 1024) a[v] = (degree[v] + 15) & ~15;  // pad16
  __syncthreads();
  int* src = a;
  int* dst = b;
  for (int off = 1; off < NN; off <<= 1) {  // Hillis-Steele inclusive scan
    for (int v = t; v < NN; v += 1024)
      dst[v] = src[v] + (v >= off ? src[v - off] : 0);
    __syncthreads();
    int* tmp = src; src = dst; dst = tmp;
  }
  for (int v = t; v < NN; v += 1024) {
    int pd = (degree[v] + 15) & ~15;
    int excl = src[v] - pd;
    row_ptr[v] = excl;
    fill_ptr[v] = excl;
  }
  if (t == 0) row_ptr[NN] = src[NN - 1];  // total padded edge count
}

__global__ __launch_bounds__(256) void csr_fill(const int* __restrict__ row,
                                                const int* __restrict__ col,
                                                int* __restrict__ fill_ptr,
                                                unsigned short* __restrict__ colidx) {
  int e = blockIdx.x * 256 + threadIdx.x;
  int pos = atomicAdd(&fill_ptr[row[e]], 1);
  colidx[pos] = (unsigned short)col[e];
}

__global__ __launch_bounds__(256) void csr_pad(const int* __restrict__ row_ptr,
                                               const int* __restrict__ degree,
                                               unsigned short* __restrict__ colidx) {
  int v = blockIdx.x * 256 + threadIdx.x;  // over NN
  int e0 = row_ptr[v] + degree[v], e1 = row_ptr[v + 1];
  for (int e = e0; e < e1; ++e) colidx[e] = (unsigned short)v;  // self-edges
}

// ---------------------------------------------------------------------------
// Greedy maximal k-independent set (k=2), single block, state in LDS.
// Round-5 gating kept (skip SEN / zero-delta sources; delta-OR exactness via
// monotone-mask + union-homomorphism). Round-6 fix: edge walks are uint4-pair
// vector loads (16 edges per 2 independent 16B loads) -> deep MLP instead of
// the serial 12-VGPR load->atomic chain that latency-bound round 5.
// ---------------------------------------------------------------------------
__global__ __launch_bounds__(1024) void mis_kernel(const int* __restrict__ row_ptr_g,
                                                   const unsigned short* __restrict__ colidx,
                                                   const int* __restrict__ rank_g,
                                                   int* __restrict__ mis_flag,
                                                   int* __restrict__ mis_list,
                                                   int* __restrict__ mis_count) {
  __shared__ int rank_s[NN];
  __shared__ int mr[NN];
  __shared__ int tmp[NN];
  __shared__ int cov[NN];
  __shared__ int dly[NN];
  __shared__ int mis_s[NN];
  __shared__ int row_ptr_s[NN + 1];
  __shared__ int done;
  __shared__ int cnt;
  int t = threadIdx.x;
  const uint4* col4 = (const uint4*)colidx;  // 8 u16 per uint4

  for (int v = t; v < NN; v += 1024) {
    int rk = rank_g[v];
    rank_s[v] = rk;
    mr[v] = rk;
    cov[v] = 0;
    mis_s[v] = 0;
    row_ptr_s[v] = row_ptr_g[v];
  }
  if (t == 0) {
    row_ptr_s[NN] = row_ptr_g[NN];
    cnt = 0;
  }
  __syncthreads();

  for (int round = 0; round < NN; ++round) {
    // --- 2 hops of min-propagation (row -> col); skip no-op sources ---
    for (int h = 0; h < 2; ++h) {
      for (int v = t; v < NN; v += 1024) tmp[v] = mr[v];
      __syncthreads();
      for (int v = t; v < NN; v += 1024) {
        int val = tmp[v];
        if (val != SEN) {
          int e0 = row_ptr_s[v];
          int nch = (row_ptr_s[v + 1] - e0) >> 3;  // even (pad16)
          const uint4* b4 = col4 + (e0 >> 3);
          for (int c = 0; c < nch; c += 2) {
            uint4 A = b4[c], B = b4[c + 1];  // independent 16B loads
            atomicMin(&mr[A.x & 0xFFFFu], val); atomicMin(&mr[A.x >> 16], val);
            atomicMin(&mr[A.y & 0xFFFFu], val); atomicMin(&mr[A.y >> 16], val);
            atomicMin(&mr[A.z & 0xFFFFu], val); atomicMin(&mr[A.z >> 16], val);
            atomicMin(&mr[A.w & 0xFFFFu], val); atomicMin(&mr[A.w >> 16], val);
            atomicMin(&mr[B.x & 0xFFFFu], val); atomicMin(&mr[B.x >> 16], val);
            atomicMin(&mr[B.y & 0xFFFFu], val); atomicMin(&mr[B.y >> 16], val);
            atomicMin(&mr[B.z & 0xFFFFu], val); atomicMin(&mr[B.z >> 16], val);
            atomicMin(&mr[B.w & 0xFFFFu], val); atomicMin(&mr[B.w >> 16], val);
          }
        }
      }
      __syncthreads();
    }
    // --- delta = newly selected; mis |= delta ---
    for (int v = t; v < NN; v += 1024) {
      int nw = (rank_s[v] == mr[v]) ? 1 : 0;
      if (nw) mis_s[v] = 1;
      dly[v] = nw;
    }
    __syncthreads();
    // --- 2 hops of OR-propagation over the delta frontier ---
    for (int h = 0; h < 2; ++h) {
      for (int v = t; v < NN; v += 1024) tmp[v] = dly[v];
      __syncthreads();
      for (int v = t; v < NN; v += 1024) {
        if (tmp[v]) {
          int e0 = row_ptr_s[v];
          int nch = (row_ptr_s[v + 1] - e0) >> 3;
          const uint4* b4 = col4 + (e0 >> 3);
          for (int c = 0; c < nch; c += 2) {
            uint4 A = b4[c], B = b4[c + 1];
            dly[A.x & 0xFFFFu] = 1; dly[A.x >> 16] = 1;
            dly[A.y & 0xFFFFu] = 1; dly[A.y >> 16] = 1;
            dly[A.z & 0xFFFFu] = 1; dly[A.z >> 16] = 1;
            dly[A.w & 0xFFFFu] = 1; dly[A.w >> 16] = 1;
            dly[B.x & 0xFFFFu] = 1; dly[B.x >> 16] = 1;
            dly[B.y & 0xFFFFu] = 1; dly[B.y >> 16] = 1;
            dly[B.z & 0xFFFFu] = 1; dly[B.z >> 16] = 1;
            dly[B.w & 0xFFFFu] = 1; dly[B.w >> 16] = 1;
          }
        }
      }
      __syncthreads();
    }
    // --- fold delta into mask; convergence check ---
    int uncov = 0;
    for (int v = t; v < NN; v += 1024) {
      int cv = cov[v] | dly[v];
      cov[v] = cv;
      uncov |= (cv == 0);
    }
    if (t == 0) done = 1;
    __syncthreads();
    if (uncov) done = 0;  // benign race: all write 0
    __syncthreads();
    if (done) break;
    for (int v = t; v < NN; v += 1024) mr[v] = cov[v] ? SEN : rank_s[v];
    __syncthreads();
  }

  for (int v = t; v < NN; v += 1024) {
    mis_flag[v] = mis_s[v];
    if (mis_s[v]) mis_list[atomicAdd(&cnt, 1)] = v;  // unordered (consumers order-free)
  }
  __syncthreads();
  if (t == 0) *mis_count = cnt;
}

// ---------------------------------------------------------------------------
// adj -> rw in place: offdiag = 0.5*adj/s', diag = adj/s' + 0.5  (s'=s>0?s:1)
// ---------------------------------------------------------------------------
__global__ __launch_bounds__(256) void rw_transform(float* __restrict__ adj,
                                                    const float* __restrict__ rowsum) {
  int idx = blockIdx.x * 256 + threadIdx.x;
  int i = idx >> 11, j = idx & (NN - 1);
  float s = rowsum[i];
  s = (s > 0.f) ? s : 1.f;
  float v = adj[idx] / s;
  adj[idx] = (i == j) ? (v + EPSV) : (v * (1.f - EPSV));
}

// ---------------------------------------------------------------------------
// Gather the M MIS columns of rw into compact Bc[t][k] (row-major, k fast).
// ---------------------------------------------------------------------------
__global__ __launch_bounds__(256) void gather_cols(const float* __restrict__ rw,
                                                   const int* __restrict__ mis_list,
                                                   const int* __restrict__ mis_count,
                                                   float* __restrict__ Bc) {
  int total = (*mis_count) * NN;
  for (int idx = blockIdx.x * 256 + threadIdx.x; idx < total; idx += gridDim.x * 256) {
    int tcol = idx >> 11, k = idx & (NN - 1);
    Bc[idx] = rw[(size_t)k * NN + mis_list[tcol]];
  }
}

// ---------------------------------------------------------------------------
// Fused c2-column + Gumbel-argmax (register-cached column slices, float4 MLP,
// deterministic shuffle tree, order-free u64 atomicMax winner fold).
// ---------------------------------------------------------------------------
__device__ inline unsigned int f32_key(float x) {
  unsigned int u = __float_as_uint(x);
  return (u & 0x80000000u) ? ~u : (u | 0x80000000u);
}
__device__ inline float dot4(float4 a, float4 b) {
  return ((a.x * b.x + a.y * b.y) + (a.z * b.z + a.w * b.w));
}

__global__ __launch_bounds__(256) void c2_argmax(const float* __restrict__ rw,
                                                 const float* __restrict__ Bc,
                                                 const float* __restrict__ u,
                                                 const int* __restrict__ mis_list,
                                                 const int* __restrict__ mis_count,
                                                 unsigned long long* __restrict__ packed) {
  int M = *mis_count;
  int njobs = M * 64;  // 64 tiles of 32 rows
  int lane = threadIdx.x & 63, w = threadIdx.x >> 6;
  for (int j = blockIdx.x; j < njobs; j += gridDim.x) {
    int tcol = j >> 6, tile = j & 63;
    int m = mis_list[tcol];
    const float4* cb = (const float4*)(Bc + (size_t)tcol * NN);
    float4 c0 = cb[lane], c1 = cb[64 + lane], c2v = cb[128 + lane], c3 = cb[192 + lane];
    float4 c4 = cb[256 + lane], c5 = cb[320 + lane], c6 = cb[384 + lane], c7 = cb[448 + lane];
    int rbase = tile * 32 + w * 8;
#pragma unroll
    for (int it = 0; it < 8; ++it) {
      int r = rbase + it;
      const float4* rp = (const float4*)(rw + (size_t)r * NN);
      float4 a0 = rp[lane], a1 = rp[64 + lane], a2 = rp[128 + lane], a3 = rp[192 + lane];
      float4 a4 = rp[256 + lane], a5 = rp[320 + lane], a6 = rp[384 + lane], a7 = rp[448 + lane];
      float s01 = dot4(a0, c0) + dot4(a1, c1);
      float s23 = dot4(a2, c2v) + dot4(a3, c3);
      float s45 = dot4(a4, c4) + dot4(a5, c5);
      float s67 = dot4(a6, c6) + dot4(a7, c7);
      float s = (s01 + s23) + (s45 + s67);
      s += __shfl_xor(s, 32);
      s += __shfl_xor(s, 16);
      s += __shfl_xor(s, 8);
      s += __shfl_xor(s, 4);
      s += __shfl_xor(s, 2);
      s += __shfl_xor(s, 1);
      if (lane == 0 && s > 0.f) {
        float uu = u[(size_t)r * NN + m];
        float g = -logf(-logf(uu + 1e-20f) + 1e-20f);
        float logit = logf(s) + g;
        unsigned long long key =
            ((unsigned long long)f32_key(logit) << 32) | (unsigned int)(NN - 1 - m);
        atomicMax(&packed[r], key);
      }
    }
  }
}

// ---------------------------------------------------------------------------
__global__ __launch_bounds__(256) void cluster_decode(const unsigned long long* __restrict__ packed,
                                                      int* __restrict__ cluster,
                                                      int* __restrict__ counts) {
  int i = blockIdx.x * 256 + threadIdx.x;
  unsigned long long p = packed[i];
  int m = (p == 0ull) ? 0 : (NN - 1 - (int)(p & 0xFFFFFFFFull));
  cluster[i] = m;
  atomicAdd(&counts[m], 1);
}

// ---------------------------------------------------------------------------
__global__ __launch_bounds__(256) void adjc_scatter(const int* __restrict__ row,
                                                    const int* __restrict__ col,
                                                    const float* __restrict__ attr,
                                                    const int* __restrict__ cluster,
                                                    float* __restrict__ adjc) {
  int e = blockIdx.x * 256 + threadIdx.x;
  int cr = cluster[row[e]], cc = cluster[col[e]];
  atomicAdd(&adjc[(size_t)cr * NN + cc], attr[e]);
}

// ---------------------------------------------------------------------------
__global__ __launch_bounds__(256) void write_chpm(const int* __restrict__ cluster,
                                                  const int* __restrict__ counts,
                                                  float* __restrict__ out_ch,
                                                  float* __restrict__ out_pinv) {
  int idx = blockIdx.x * 256 + threadIdx.x;  // over N*N
  int a = idx >> 11, b = idx & (NN - 1);
  out_ch[idx] = (cluster[a] == b) ? 1.f : 0.f;
  float pv = 0.f;
  if (cluster[b] == a) {
    int c = counts[a];
    pv = 1.f / (float)(c > 0 ? c : 1);
  }
  out_pinv[idx] = pv;
}

// ---------------------------------------------------------------------------
__global__ __launch_bounds__(256) void write_mis(const int* __restrict__ mis_flag,
                                                 float* __restrict__ out_mis) {
  int i = blockIdx.x * 256 + threadIdx.x;
  out_mis[i] = mis_flag[i] ? 1.f : 0.f;
}

// ---------------------------------------------------------------------------
__global__ __launch_bounds__(256) void xpool_scatter(const float* __restrict__ x,
                                                     const int* __restrict__ cluster,
                                                     float* __restrict__ xp) {
  int idx = blockIdx.x * 256 + threadIdx.x;  // over N*D
  int i = idx >> 9;
  atomicAdd(&xp[cluster[i] * DD + (idx & (DD - 1))], x[idx]);
}

__global__ __launch_bounds__(256) void xpool_scale(float* __restrict__ xp,
                                                   const int* __restrict__ counts) {
  int idx = blockIdx.x * 256 + threadIdx.x;
  int c = counts[idx >> 9];
  xp[idx] = xp[idx] / (float)(c > 0 ? c : 1);
}

// ---------------------------------------------------------------------------
extern "C" void kernel_launch(void* const* d_in, const int* in_sizes, int n_in,
                              void* d_out, int out_size, void* d_ws, size_t ws_size,
                              hipStream_t stream) {
  const int*   edge_index = (const int*)d_in[0];
  const float* edge_attr  = (const float*)d_in[1];
  const float* x          = (const float*)d_in[2];
  const int*   rank       = (const int*)d_in[3];
  const float* u          = (const float*)d_in[4];
  float* out              = (float*)d_out;  // f32 outputs, concatenated

  const int* row = edge_index;
  const int* col = edge_index + EE;

  float* out_adjc = out;                 // N*N — doubles as adj/rw scratch
  float* out_ch   = out + SZ;            // N*N — doubles as Bc scratch
  float* out_pinv = out + 2 * SZ;        // N*N
  float* out_mis  = out + 3 * SZ;        // N
  float* out_xp   = out + 3 * SZ + NN;   // N*D

  // d_ws layout (~280 KB)
  unsigned long long* packed = (unsigned long long*)d_ws;  // N u64
  float* rowsum    = (float*)(packed + NN);                // N
  int*   counts    = (int*)(rowsum + NN);                  // N
  int*   mis_flag  = counts + NN;                          // N
  int*   cluster   = mis_flag + NN;                        // N
  int*   mis_list  = cluster + NN;                         // N
  int*   mis_count = mis_list + NN;                        // 1
  int*   degree    = mis_count + 1;                        // N (must be zeroed)
  int*   fill_ptr  = degree + NN;                          // N
  int*   row_ptr   = fill_ptr + NN;                        // N+1
  unsigned short* colidx =                                  // padded E (<=96256) u16, 32B-aligned
      (unsigned short*)(((uintptr_t)(row_ptr + NN + 1) + 31) & ~(uintptr_t)31);

  hipMemsetAsync(out_adjc, 0, SZ * sizeof(float), stream);
  hipMemsetAsync(out_xp, 0, (size_t)NN * DD * sizeof(float), stream);
  // zero packed..degree (later arrays are fully written before read)
  hipMemsetAsync(d_ws, 0, NN * sizeof(unsigned long long) + (6 * NN + 1) * sizeof(int), stream);

  build_adj<<<EE / 256, 256, 0, stream>>>(row, col, edge_attr, out_adjc, rowsum);
  csr_count<<<EE / 256, 256, 0, stream>>>(row, degree);
  csr_scan<<<1, 1024, 0, stream>>>(degree, row_ptr, fill_ptr);
  csr_fill<<<EE / 256, 256, 0, stream>>>(row, col, fill_ptr, colidx);
  csr_pad<<<NN / 256, 256, 0, stream>>>(row_ptr, degree, colidx);
  mis_kernel<<<1, 1024, 0, stream>>>(row_ptr, colidx, rank, mis_flag, mis_list, mis_count);
  rw_transform<<<(NN * NN) / 256, 256, 0, stream>>>(out_adjc, rowsum);
  gather_cols<<<256, 256, 0, stream>>>(out_adjc, mis_list, mis_count, out_ch);
  c2_argmax<<<2048, 256, 0, stream>>>(out_adjc, out_ch, u, mis_list, mis_count, packed);
  cluster_decode<<<NN / 256, 256, 0, stream>>>(packed, cluster, counts);

  // rw no longer needed: rewrite the region with the real adj_c
  hipMemsetAsync(out_adjc, 0, SZ * sizeof(float), stream);
  adjc_scatter<<<EE / 256, 256, 0, stream>>>(row, col, edge_attr, cluster, out_adjc);

  write_chpm<<<(NN * NN) / 256, 256, 0, stream>>>(cluster, counts, out_ch, out_pinv);
  write_mis<<<NN / 256, 256, 0, stream>>>(mis_flag, out_mis);
  xpool_scatter<<<(NN * DD) / 256, 256, 0, stream>>>(x, cluster, out_xp);
  xpool_scale<<<(NN * DD) / 256, 256, 0, stream>>>(out_xp, counts);
}